// Round 1
// baseline (1115.051 us; speedup 1.0000x reference)
//
#include <hip/hip_runtime.h>
#include <math.h>

#define B_    4
#define C_    256
#define N_    2304      // 48*48 tokens
#define H_    8
#define DH_   64
#define IN_   512       // heads*dim_head
#define ROWS_ 9216      // B_*N_

// ---------------------------------------------------------------------------
// x[b][c][n] -> T[b][n][c]   (32x32 LDS tile transpose)
__global__ __launch_bounds__(256)
void k_transpose_in(const float* __restrict__ x, float* __restrict__ T) {
    __shared__ float tile[32][33];
    int bb = blockIdx.z;
    int nBase = blockIdx.x * 32;
    int cBase = blockIdx.y * 32;
    int tx = threadIdx.x, ty = threadIdx.y;
    const float* xp = x + (size_t)bb * C_ * N_;
    #pragma unroll
    for (int i = 0; i < 32; i += 8)
        tile[ty + i][tx] = xp[(size_t)(cBase + ty + i) * N_ + nBase + tx];
    __syncthreads();
    float* Tp = T + (size_t)bb * N_ * C_;
    #pragma unroll
    for (int i = 0; i < 32; i += 8)
        Tp[(size_t)(nBase + ty + i) * C_ + cBase + tx] = tile[tx][ty + i];
}

// ---------------------------------------------------------------------------
// row LayerNorm over C_=256: one wave per row, 4 floats/lane
__global__ __launch_bounds__(256)
void k_layernorm(const float* __restrict__ in, float* __restrict__ out,
                 const float* __restrict__ g, const float* __restrict__ b) {
    int wv = threadIdx.x >> 6;
    int lane = threadIdx.x & 63;
    int row = blockIdx.x * 4 + wv;
    float4 v = ((const float4*)(in + (size_t)row * C_))[lane];
    float s = v.x + v.y + v.z + v.w;
    #pragma unroll
    for (int m = 1; m < 64; m <<= 1) s += __shfl_xor(s, m);
    float mean = s * (1.0f / C_);
    float dx = v.x - mean, dy = v.y - mean, dz = v.z - mean, dw = v.w - mean;
    float s2 = dx * dx + dy * dy + dz * dz + dw * dw;
    #pragma unroll
    for (int m = 1; m < 64; m <<= 1) s2 += __shfl_xor(s2, m);
    float rs = rsqrtf(s2 * (1.0f / C_) + 1e-5f);
    float4 gv = ((const float4*)g)[lane];
    float4 bv = ((const float4*)b)[lane];
    float4 o;
    o.x = dx * rs * gv.x + bv.x;
    o.y = dy * rs * gv.y + bv.y;
    o.z = dz * rs * gv.z + bv.z;
    o.w = dw * rs * gv.w + bv.w;
    ((float4*)(out + (size_t)row * C_))[lane] = o;
}

// ---------------------------------------------------------------------------
__device__ __forceinline__ float gelu_exact(float x) {
    return 0.5f * x * (1.0f + erff(x * 0.70710678118654752440f));
}

// C = A[M,K] @ Bw[K,N], 64x64 tile, BK=16, 256 thr, 4x4 microtile.
// EP: 0 none | 1 +bias | 2 +bias+Res | 3 gelu(x+bias)
template <int EP>
__global__ __launch_bounds__(256)
void k_gemm(const float* __restrict__ A, const float* __restrict__ Bw,
            float* __restrict__ Cm, const float* __restrict__ bias,
            const float* __restrict__ Res, int M, int N, int K) {
    __shared__ float As[16][68];   // [k][row]  (A staged transposed)
    __shared__ float Bs[16][68];   // [k][col]
    int tid = threadIdx.x;
    int tx = tid & 15, ty = tid >> 4;
    int rowBase = blockIdx.y * 64;
    int colBase = blockIdx.x * 64;
    int arow = tid >> 2;            // 0..63
    int ak   = (tid & 3) << 2;      // 0,4,8,12
    int bk   = tid >> 4;            // 0..15
    int bcol = (tid & 15) << 2;     // 0..60
    float acc[4][4] = {};
    for (int k0 = 0; k0 < K; k0 += 16) {
        float4 av = *(const float4*)(A + (size_t)(rowBase + arow) * K + k0 + ak);
        float4 bv = *(const float4*)(Bw + (size_t)(k0 + bk) * N + colBase + bcol);
        __syncthreads();
        As[ak + 0][arow] = av.x;
        As[ak + 1][arow] = av.y;
        As[ak + 2][arow] = av.z;
        As[ak + 3][arow] = av.w;
        *(float4*)&Bs[bk][bcol] = bv;
        __syncthreads();
        #pragma unroll
        for (int kk = 0; kk < 16; ++kk) {
            float4 a = *(const float4*)&As[kk][ty << 2];
            float4 b = *(const float4*)&Bs[kk][tx << 2];
            float ar[4] = {a.x, a.y, a.z, a.w};
            float br[4] = {b.x, b.y, b.z, b.w};
            #pragma unroll
            for (int i = 0; i < 4; ++i)
                #pragma unroll
                for (int j = 0; j < 4; ++j) acc[i][j] += ar[i] * br[j];
        }
    }
    int r0 = rowBase + (ty << 2);
    int c0 = colBase + (tx << 2);
    float4 bv4 = make_float4(0.f, 0.f, 0.f, 0.f);
    if (EP >= 1) bv4 = *(const float4*)(bias + c0);
    #pragma unroll
    for (int i = 0; i < 4; ++i) {
        float o0 = acc[i][0] + bv4.x;
        float o1 = acc[i][1] + bv4.y;
        float o2 = acc[i][2] + bv4.z;
        float o3 = acc[i][3] + bv4.w;
        if (EP == 3) {
            o0 = gelu_exact(o0); o1 = gelu_exact(o1);
            o2 = gelu_exact(o2); o3 = gelu_exact(o3);
        }
        if (EP == 2) {
            float4 rv = *(const float4*)(Res + (size_t)(r0 + i) * N + c0);
            o0 += rv.x; o1 += rv.y; o2 += rv.z; o3 += rv.w;
        }
        *(float4*)(Cm + (size_t)(r0 + i) * N + c0) = make_float4(o0, o1, o2, o3);
    }
}

// ---------------------------------------------------------------------------
// Flash attention, fp32. One block = 64 query rows of one (b,h).
// Q/K staged transposed [d][row], V natural [k][d], P transposed [k][q].
__global__ __launch_bounds__(256)
void k_flash_attn(const float* __restrict__ Q, const float* __restrict__ K,
                  const float* __restrict__ V, float* __restrict__ O) {
    __shared__ float Qs[64][68];   // [d][q] pre-scaled
    __shared__ float Ks[64][68];   // [d][k]
    __shared__ float Vs[64][68];   // [k][d]
    __shared__ float Ps[64][68];   // [k][q]
    int tid = threadIdx.x;
    int tx = tid & 15, ty = tid >> 4;
    int bh = blockIdx.y;
    int bb = bh >> 3, h = bh & 7;
    int qBase = blockIdx.x * 64;
    const float* Qp = Q + (size_t)bb * N_ * IN_ + h * DH_;
    const float* Kp = K + (size_t)bb * N_ * IN_ + h * DH_;
    const float* Vp = V + (size_t)bb * N_ * IN_ + h * DH_;
    int lr = tid >> 4;           // 0..15
    int lc = (tid & 15) << 2;    // 0..60
    const float scale = 0.125f;  // 1/sqrt(64)
    #pragma unroll
    for (int p = 0; p < 4; ++p) {
        int r = lr + p * 16;
        float4 qv = *(const float4*)(Qp + (size_t)(qBase + r) * IN_ + lc);
        Qs[lc + 0][r] = qv.x * scale;
        Qs[lc + 1][r] = qv.y * scale;
        Qs[lc + 2][r] = qv.z * scale;
        Qs[lc + 3][r] = qv.w * scale;
    }
    float m_i[4], l_i[4], acc[4][4] = {};
    #pragma unroll
    for (int i = 0; i < 4; ++i) { m_i[i] = -1e30f; l_i[i] = 0.f; }

    for (int kt = 0; kt < N_; kt += 64) {
        __syncthreads();
        #pragma unroll
        for (int p = 0; p < 4; ++p) {
            int r = lr + p * 16;
            float4 kv = *(const float4*)(Kp + (size_t)(kt + r) * IN_ + lc);
            Ks[lc + 0][r] = kv.x;
            Ks[lc + 1][r] = kv.y;
            Ks[lc + 2][r] = kv.z;
            Ks[lc + 3][r] = kv.w;
            float4 vv = *(const float4*)(Vp + (size_t)(kt + r) * IN_ + lc);
            *(float4*)&Vs[r][lc] = vv;
        }
        __syncthreads();
        // S tile: q rows ty*4+i, k cols tx*4+j
        float s[4][4] = {};
        #pragma unroll 8
        for (int d = 0; d < 64; ++d) {
            float4 a = *(const float4*)&Qs[d][ty << 2];
            float4 b = *(const float4*)&Ks[d][tx << 2];
            float ar[4] = {a.x, a.y, a.z, a.w};
            float br[4] = {b.x, b.y, b.z, b.w};
            #pragma unroll
            for (int i = 0; i < 4; ++i)
                #pragma unroll
                for (int j = 0; j < 4; ++j) s[i][j] += ar[i] * br[j];
        }
        // online softmax (rows live in 16 consecutive lanes: same ty)
        #pragma unroll
        for (int i = 0; i < 4; ++i) {
            float mx = fmaxf(fmaxf(s[i][0], s[i][1]), fmaxf(s[i][2], s[i][3]));
            mx = fmaxf(mx, __shfl_xor(mx, 1));
            mx = fmaxf(mx, __shfl_xor(mx, 2));
            mx = fmaxf(mx, __shfl_xor(mx, 4));
            mx = fmaxf(mx, __shfl_xor(mx, 8));
            float mnew = fmaxf(m_i[i], mx);
            float p0 = __expf(s[i][0] - mnew);
            float p1 = __expf(s[i][1] - mnew);
            float p2 = __expf(s[i][2] - mnew);
            float p3 = __expf(s[i][3] - mnew);
            float sum = p0 + p1 + p2 + p3;
            sum += __shfl_xor(sum, 1);
            sum += __shfl_xor(sum, 2);
            sum += __shfl_xor(sum, 4);
            sum += __shfl_xor(sum, 8);
            float co = __expf(m_i[i] - mnew);
            l_i[i] = l_i[i] * co + sum;
            m_i[i] = mnew;
            #pragma unroll
            for (int j = 0; j < 4; ++j) acc[i][j] *= co;
            int qcol = (ty << 2) + i;
            Ps[(tx << 2) + 0][qcol] = p0;
            Ps[(tx << 2) + 1][qcol] = p1;
            Ps[(tx << 2) + 2][qcol] = p2;
            Ps[(tx << 2) + 3][qcol] = p3;
        }
        __syncthreads();
        // acc[q][d] += P[q][k] * V[k][d]
        #pragma unroll 8
        for (int kk = 0; kk < 64; ++kk) {
            float4 pa = *(const float4*)&Ps[kk][ty << 2];
            float4 vb = *(const float4*)&Vs[kk][tx << 2];
            float ar[4] = {pa.x, pa.y, pa.z, pa.w};
            float br[4] = {vb.x, vb.y, vb.z, vb.w};
            #pragma unroll
            for (int i = 0; i < 4; ++i)
                #pragma unroll
                for (int j = 0; j < 4; ++j) acc[i][j] += ar[i] * br[j];
        }
    }
    float* Op = O + (size_t)bb * N_ * IN_ + h * DH_;
    #pragma unroll
    for (int i = 0; i < 4; ++i) {
        float inv = 1.0f / l_i[i];
        float4 ov = make_float4(acc[i][0] * inv, acc[i][1] * inv,
                                acc[i][2] * inv, acc[i][3] * inv);
        *(float4*)(Op + (size_t)(qBase + (ty << 2) + i) * IN_ + (tx << 2)) = ov;
    }
}

// ---------------------------------------------------------------------------
// y[b,o,n] = sum_c T3[b,n,c]*Wp[c,o] + bp[o] + x[b,o,n]  (transposed store)
__global__ __launch_bounds__(256)
void k_final_conv(const float* __restrict__ A, const float* __restrict__ Wp,
                  const float* __restrict__ bp, const float* __restrict__ x,
                  float* __restrict__ out) {
    __shared__ float As[16][68];
    __shared__ float Bs[16][68];
    __shared__ float Cs[64][68];   // [o][n]
    int tid = threadIdx.x;
    int tx = tid & 15, ty = tid >> 4;
    int rowBase = blockIdx.y * 64;   // global row (b*N_ + n)
    int colBase = blockIdx.x * 64;   // output channel o
    int arow = tid >> 2;
    int ak   = (tid & 3) << 2;
    int bk   = tid >> 4;
    int bcol = (tid & 15) << 2;
    float acc[4][4] = {};
    for (int k0 = 0; k0 < C_; k0 += 16) {
        float4 av = *(const float4*)(A + (size_t)(rowBase + arow) * C_ + k0 + ak);
        float4 bv = *(const float4*)(Wp + (size_t)(k0 + bk) * C_ + colBase + bcol);
        __syncthreads();
        As[ak + 0][arow] = av.x;
        As[ak + 1][arow] = av.y;
        As[ak + 2][arow] = av.z;
        As[ak + 3][arow] = av.w;
        *(float4*)&Bs[bk][bcol] = bv;
        __syncthreads();
        #pragma unroll
        for (int kk = 0; kk < 16; ++kk) {
            float4 a = *(const float4*)&As[kk][ty << 2];
            float4 b = *(const float4*)&Bs[kk][tx << 2];
            float ar[4] = {a.x, a.y, a.z, a.w};
            float br[4] = {b.x, b.y, b.z, b.w};
            #pragma unroll
            for (int i = 0; i < 4; ++i)
                #pragma unroll
                for (int j = 0; j < 4; ++j) acc[i][j] += ar[i] * br[j];
        }
    }
    // transpose through LDS: Cs[o_local][n_local]
    __syncthreads();
    #pragma unroll
    for (int i = 0; i < 4; ++i)
        #pragma unroll
        for (int j = 0; j < 4; ++j)
            Cs[(tx << 2) + j][(ty << 2) + i] = acc[i][j];
    __syncthreads();
    int bb = rowBase / N_;          // tiles never straddle batch (2304%64==0)
    int nBase = rowBase % N_;
    #pragma unroll
    for (int p = 0; p < 4; ++p) {
        int ol = (tid >> 4) + p * 16;
        int nl = (tid & 15) << 2;
        int o = colBase + ol;
        size_t oidx = ((size_t)(bb * C_ + o)) * N_ + nBase + nl;
        float4 cv = *(const float4*)&Cs[ol][nl];
        float4 xv = *(const float4*)(x + oidx);
        float bo_ = bp[o];
        *(float4*)(out + oidx) = make_float4(cv.x + bo_ + xv.x, cv.y + bo_ + xv.y,
                                             cv.z + bo_ + xv.z, cv.w + bo_ + xv.w);
    }
}

// ---------------------------------------------------------------------------
extern "C" void kernel_launch(void* const* d_in, const int* in_sizes, int n_in,
                              void* d_out, int out_size, void* d_ws, size_t ws_size,
                              hipStream_t stream) {
    (void)in_sizes; (void)n_in; (void)out_size; (void)ws_size;
    const float* x   = (const float*)d_in[0];
    const float* Wq  = (const float*)d_in[1];
    const float* Wk  = (const float*)d_in[2];
    const float* Wv  = (const float*)d_in[3];
    const float* Wo  = (const float*)d_in[4];
    const float* bo  = (const float*)d_in[5];
    const float* g1  = (const float*)d_in[6];
    const float* b1  = (const float*)d_in[7];
    const float* g2  = (const float*)d_in[8];
    const float* b2  = (const float*)d_in[9];
    const float* Wf1 = (const float*)d_in[10];
    const float* bf1 = (const float*)d_in[11];
    const float* Wf2 = (const float*)d_in[12];
    const float* bf2 = (const float*)d_in[13];
    const float* Wp  = (const float*)d_in[14];
    const float* bp  = (const float*)d_in[15];
    float* out = (float*)d_out;
    float* ws  = (float*)d_ws;

    float* T  = ws;                       // [9216,256]
    float* T2 = ws + 2359296;             // [9216,256]
    float* TN = ws + 4718592;             // [9216,256]
    float* Qb = ws + 7077888;             // [9216,512]
    float* Kb = ws + 11796480;            // [9216,512]
    float* Vb = ws + 16515072;            // [9216,512]
    float* Ob = ws + 21233664;            // [9216,512]
    float* F  = Qb;                       // reuse after attention

    k_transpose_in<<<dim3(72, 8, 4), dim3(32, 8), 0, stream>>>(x, T);
    k_layernorm<<<2304, 256, 0, stream>>>(T, TN, g1, b1);
    k_gemm<0><<<dim3(8, 144), 256, 0, stream>>>(TN, Wq, Qb, nullptr, nullptr, ROWS_, IN_, C_);
    k_gemm<0><<<dim3(8, 144), 256, 0, stream>>>(TN, Wk, Kb, nullptr, nullptr, ROWS_, IN_, C_);
    k_gemm<0><<<dim3(8, 144), 256, 0, stream>>>(TN, Wv, Vb, nullptr, nullptr, ROWS_, IN_, C_);
    k_flash_attn<<<dim3(36, 32), 256, 0, stream>>>(Qb, Kb, Vb, Ob);
    k_gemm<2><<<dim3(4, 144), 256, 0, stream>>>(Ob, Wo, T2, bo, T, ROWS_, C_, IN_);
    k_layernorm<<<2304, 256, 0, stream>>>(T2, TN, g2, b2);
    k_gemm<3><<<dim3(8, 144), 256, 0, stream>>>(TN, Wf1, F, bf1, nullptr, ROWS_, IN_, C_);
    k_gemm<2><<<dim3(4, 144), 256, 0, stream>>>(F, Wf2, T, bf2, T2, ROWS_, C_, IN_);
    k_final_conv<<<dim3(4, 144), 256, 0, stream>>>(T, Wp, bp, x, out);
}

// Round 2
// 493.391 us; speedup vs baseline: 2.2600x; 2.2600x over previous
//
#include <hip/hip_runtime.h>
#include <math.h>

#define B_    4
#define C_    256
#define N_    2304      // 48*48 tokens
#define H_    8
#define DH_   64
#define IN_   512       // heads*dim_head
#define ROWS_ 9216      // B_*N_

typedef __attribute__((ext_vector_type(8))) short short8;
typedef __attribute__((ext_vector_type(4))) float f32x4;

__device__ __forceinline__ unsigned short f2bf(float f) {
    unsigned int u = __float_as_uint(f);
    u += 0x7fffu + ((u >> 16) & 1u);    // round-to-nearest-even
    return (unsigned short)(u >> 16);
}

// ---------------------------------------------------------------------------
// x[b][c][n] -> T[b][n][c]   (32x32 LDS tile transpose)
__global__ __launch_bounds__(256)
void k_transpose_in(const float* __restrict__ x, float* __restrict__ T) {
    __shared__ float tile[32][33];
    int bb = blockIdx.z;
    int nBase = blockIdx.x * 32;
    int cBase = blockIdx.y * 32;
    int tx = threadIdx.x, ty = threadIdx.y;
    const float* xp = x + (size_t)bb * C_ * N_;
    #pragma unroll
    for (int i = 0; i < 32; i += 8)
        tile[ty + i][tx] = xp[(size_t)(cBase + ty + i) * N_ + nBase + tx];
    __syncthreads();
    float* Tp = T + (size_t)bb * N_ * C_;
    #pragma unroll
    for (int i = 0; i < 32; i += 8)
        Tp[(size_t)(nBase + ty + i) * C_ + cBase + tx] = tile[tx][ty + i];
}

// ---------------------------------------------------------------------------
// row LayerNorm over C_=256: one wave per row, 4 floats/lane
__global__ __launch_bounds__(256)
void k_layernorm(const float* __restrict__ in, float* __restrict__ out,
                 const float* __restrict__ g, const float* __restrict__ b) {
    int wv = threadIdx.x >> 6;
    int lane = threadIdx.x & 63;
    int row = blockIdx.x * 4 + wv;
    float4 v = ((const float4*)(in + (size_t)row * C_))[lane];
    float s = v.x + v.y + v.z + v.w;
    #pragma unroll
    for (int m = 1; m < 64; m <<= 1) s += __shfl_xor(s, m);
    float mean = s * (1.0f / C_);
    float dx = v.x - mean, dy = v.y - mean, dz = v.z - mean, dw = v.w - mean;
    float s2 = dx * dx + dy * dy + dz * dz + dw * dw;
    #pragma unroll
    for (int m = 1; m < 64; m <<= 1) s2 += __shfl_xor(s2, m);
    float rs = rsqrtf(s2 * (1.0f / C_) + 1e-5f);
    float4 gv = ((const float4*)g)[lane];
    float4 bv = ((const float4*)b)[lane];
    float4 o;
    o.x = dx * rs * gv.x + bv.x;
    o.y = dy * rs * gv.y + bv.y;
    o.z = dz * rs * gv.z + bv.z;
    o.w = dw * rs * gv.w + bv.w;
    ((float4*)(out + (size_t)row * C_))[lane] = o;
}

// ---------------------------------------------------------------------------
__device__ __forceinline__ float gelu_exact(float x) {
    return 0.5f * x * (1.0f + erff(x * 0.70710678118654752440f));
}

// C = A[M,K] @ Bw[K,N], 64x64 tile, BK=16, 256 thr, 4x4 microtile, fp32 out.
// EP: 0 none | 1 +bias | 2 +bias+Res | 3 gelu(x+bias)
template <int EP>
__global__ __launch_bounds__(256)
void k_gemm(const float* __restrict__ A, const float* __restrict__ Bw,
            float* __restrict__ Cm, const float* __restrict__ bias,
            const float* __restrict__ Res, int M, int N, int K) {
    __shared__ float As[16][68];   // [k][row]  (A staged transposed)
    __shared__ float Bs[16][68];   // [k][col]
    int tid = threadIdx.x;
    int tx = tid & 15, ty = tid >> 4;
    int rowBase = blockIdx.y * 64;
    int colBase = blockIdx.x * 64;
    int arow = tid >> 2;            // 0..63
    int ak   = (tid & 3) << 2;      // 0,4,8,12
    int bk   = tid >> 4;            // 0..15
    int bcol = (tid & 15) << 2;     // 0..60
    float acc[4][4] = {};
    for (int k0 = 0; k0 < K; k0 += 16) {
        float4 av = *(const float4*)(A + (size_t)(rowBase + arow) * K + k0 + ak);
        float4 bv = *(const float4*)(Bw + (size_t)(k0 + bk) * N + colBase + bcol);
        __syncthreads();
        As[ak + 0][arow] = av.x;
        As[ak + 1][arow] = av.y;
        As[ak + 2][arow] = av.z;
        As[ak + 3][arow] = av.w;
        *(float4*)&Bs[bk][bcol] = bv;
        __syncthreads();
        #pragma unroll
        for (int kk = 0; kk < 16; ++kk) {
            float4 a = *(const float4*)&As[kk][ty << 2];
            float4 b = *(const float4*)&Bs[kk][tx << 2];
            float ar[4] = {a.x, a.y, a.z, a.w};
            float br[4] = {b.x, b.y, b.z, b.w};
            #pragma unroll
            for (int i = 0; i < 4; ++i)
                #pragma unroll
                for (int j = 0; j < 4; ++j) acc[i][j] += ar[i] * br[j];
        }
    }
    int r0 = rowBase + (ty << 2);
    int c0 = colBase + (tx << 2);
    float4 bv4 = make_float4(0.f, 0.f, 0.f, 0.f);
    if (EP >= 1) bv4 = *(const float4*)(bias + c0);
    #pragma unroll
    for (int i = 0; i < 4; ++i) {
        float o0 = acc[i][0] + bv4.x;
        float o1 = acc[i][1] + bv4.y;
        float o2 = acc[i][2] + bv4.z;
        float o3 = acc[i][3] + bv4.w;
        if (EP == 3) {
            o0 = gelu_exact(o0); o1 = gelu_exact(o1);
            o2 = gelu_exact(o2); o3 = gelu_exact(o3);
        }
        if (EP == 2) {
            float4 rv = *(const float4*)(Res + (size_t)(r0 + i) * N + c0);
            o0 += rv.x; o1 += rv.y; o2 += rv.z; o3 += rv.w;
        }
        *(float4*)(Cm + (size_t)(r0 + i) * N + c0) = make_float4(o0, o1, o2, o3);
    }
}

// Same GEMM, bf16 packed store (for Q, K producers).
__global__ __launch_bounds__(256)
void k_gemm_qk(const float* __restrict__ A, const float* __restrict__ Bw,
               unsigned short* __restrict__ Cm, int M, int N, int K) {
    __shared__ float As[16][68];
    __shared__ float Bs[16][68];
    int tid = threadIdx.x;
    int tx = tid & 15, ty = tid >> 4;
    int rowBase = blockIdx.y * 64;
    int colBase = blockIdx.x * 64;
    int arow = tid >> 2;
    int ak   = (tid & 3) << 2;
    int bk   = tid >> 4;
    int bcol = (tid & 15) << 2;
    float acc[4][4] = {};
    for (int k0 = 0; k0 < K; k0 += 16) {
        float4 av = *(const float4*)(A + (size_t)(rowBase + arow) * K + k0 + ak);
        float4 bv = *(const float4*)(Bw + (size_t)(k0 + bk) * N + colBase + bcol);
        __syncthreads();
        As[ak + 0][arow] = av.x;
        As[ak + 1][arow] = av.y;
        As[ak + 2][arow] = av.z;
        As[ak + 3][arow] = av.w;
        *(float4*)&Bs[bk][bcol] = bv;
        __syncthreads();
        #pragma unroll
        for (int kk = 0; kk < 16; ++kk) {
            float4 a = *(const float4*)&As[kk][ty << 2];
            float4 b = *(const float4*)&Bs[kk][tx << 2];
            float ar[4] = {a.x, a.y, a.z, a.w};
            float br[4] = {b.x, b.y, b.z, b.w};
            #pragma unroll
            for (int i = 0; i < 4; ++i)
                #pragma unroll
                for (int j = 0; j < 4; ++j) acc[i][j] += ar[i] * br[j];
        }
    }
    int r0 = rowBase + (ty << 2);
    int c0 = colBase + (tx << 2);
    #pragma unroll
    for (int i = 0; i < 4; ++i) {
        ushort4 o;
        o.x = f2bf(acc[i][0]); o.y = f2bf(acc[i][1]);
        o.z = f2bf(acc[i][2]); o.w = f2bf(acc[i][3]);
        *(ushort4*)(Cm + (size_t)(r0 + i) * N + c0) = o;
    }
}

// Same GEMM, transposed bf16 store: Vt[(b*IN_ + col)][n] (for V producer).
__global__ __launch_bounds__(256)
void k_gemm_vt(const float* __restrict__ A, const float* __restrict__ Bw,
               unsigned short* __restrict__ Vt, int M, int N, int K) {
    __shared__ float As[16][68];
    __shared__ float Bs[16][68];
    __shared__ float Cs[64][68];
    int tid = threadIdx.x;
    int tx = tid & 15, ty = tid >> 4;
    int rowBase = blockIdx.y * 64;
    int colBase = blockIdx.x * 64;
    int arow = tid >> 2;
    int ak   = (tid & 3) << 2;
    int bk   = tid >> 4;
    int bcol = (tid & 15) << 2;
    float acc[4][4] = {};
    for (int k0 = 0; k0 < K; k0 += 16) {
        float4 av = *(const float4*)(A + (size_t)(rowBase + arow) * K + k0 + ak);
        float4 bv = *(const float4*)(Bw + (size_t)(k0 + bk) * N + colBase + bcol);
        __syncthreads();
        As[ak + 0][arow] = av.x;
        As[ak + 1][arow] = av.y;
        As[ak + 2][arow] = av.z;
        As[ak + 3][arow] = av.w;
        *(float4*)&Bs[bk][bcol] = bv;
        __syncthreads();
        #pragma unroll
        for (int kk = 0; kk < 16; ++kk) {
            float4 a = *(const float4*)&As[kk][ty << 2];
            float4 b = *(const float4*)&Bs[kk][tx << 2];
            float ar[4] = {a.x, a.y, a.z, a.w};
            float br[4] = {b.x, b.y, b.z, b.w};
            #pragma unroll
            for (int i = 0; i < 4; ++i)
                #pragma unroll
                for (int j = 0; j < 4; ++j) acc[i][j] += ar[i] * br[j];
        }
    }
    __syncthreads();
    #pragma unroll
    for (int i = 0; i < 4; ++i)
        #pragma unroll
        for (int j = 0; j < 4; ++j)
            Cs[(tx << 2) + j][(ty << 2) + i] = acc[i][j];
    __syncthreads();
    int bb = rowBase / N_;
    int nBase = rowBase % N_;
    #pragma unroll
    for (int p = 0; p < 4; ++p) {
        int ol = (tid >> 4) + p * 16;
        int nl = (tid & 15) << 2;
        ushort4 o;
        o.x = f2bf(Cs[ol][nl + 0]); o.y = f2bf(Cs[ol][nl + 1]);
        o.z = f2bf(Cs[ol][nl + 2]); o.w = f2bf(Cs[ol][nl + 3]);
        *(ushort4*)(Vt + ((size_t)bb * IN_ + colBase + ol) * N_ + nBase + nl) = o;
    }
}

// ---------------------------------------------------------------------------
// MFMA flash attention. Block = 256 thr = 4 waves; 64 q-rows per block
// (16 per wave); KV tile = 64. Q/K/V bf16 in XOR-swizzled LDS.
// Qb,Kb: [b][n][512] bf16 ; Vt: [b][512][n] bf16 ; Ob: [b][n][512] fp32.
#define CEXP 0.18033688f   // (1/sqrt(64)) * log2(e)

__device__ __forceinline__ const short8* frg(const short* base, int row, int chunk) {
    return (const short8*)(base + (row << 6) + (((chunk) ^ (row & 7)) << 3));
}

__global__ __launch_bounds__(256)
void k_flash_mfma(const short* __restrict__ Qb, const short* __restrict__ Kb,
                  const short* __restrict__ Vt, float* __restrict__ Ob) {
    __shared__ __align__(16) short Qs[64 * 64];
    __shared__ __align__(16) short Ks[64 * 64];
    __shared__ __align__(16) short Vs[64 * 64];   // [d][kv]
    __shared__ __align__(16) short Ps[4][16 * 64];
    int tid = threadIdx.x;
    int w = tid >> 6;           // wave 0..3
    int lane = tid & 63;
    int l15 = lane & 15;
    int g = lane >> 4;          // 0..3
    int bh = blockIdx.y;
    int bb = bh >> 3, h = bh & 7;
    int qBase = blockIdx.x * 64;

    const short* Qp = Qb + ((size_t)bb * N_ + qBase) * IN_ + h * DH_;
    const short* Kp = Kb + (size_t)bb * N_ * IN_ + h * DH_;
    const short* Vp = Vt + ((size_t)bb * IN_ + h * DH_) * N_;

    // stage Q (swizzled): 512 16B-chunks, 2 per thread
    #pragma unroll
    for (int tt = 0; tt < 2; ++tt) {
        int t = tid + tt * 256;
        int r = t >> 3, c = t & 7;
        *(uint4*)(Qs + (r << 6) + ((c ^ (r & 7)) << 3)) =
            *(const uint4*)(Qp + (size_t)r * IN_ + c * 8);
    }
    __syncthreads();
    short8 qf0 = *frg(Qs, w * 16 + l15, g);
    short8 qf1 = *frg(Qs, w * 16 + l15, 4 + g);

    float m_r[4], l_r[4];
    f32x4 oacc[4];
    #pragma unroll
    for (int i = 0; i < 4; ++i) {
        m_r[i] = -1e30f; l_r[i] = 0.f;
        oacc[i] = (f32x4){0.f, 0.f, 0.f, 0.f};
    }
    short* Ps_w = Ps[w];

    for (int kt = 0; kt < N_; kt += 64) {
        __syncthreads();   // prior tile reads complete
        #pragma unroll
        for (int tt = 0; tt < 2; ++tt) {
            int t = tid + tt * 256;
            int r = t >> 3, c = t & 7;
            *(uint4*)(Ks + (r << 6) + ((c ^ (r & 7)) << 3)) =
                *(const uint4*)(Kp + (size_t)(kt + r) * IN_ + c * 8);
            *(uint4*)(Vs + (r << 6) + ((c ^ (r & 7)) << 3)) =
                *(const uint4*)(Vp + (size_t)r * N_ + kt + c * 8);
        }
        __syncthreads();

        // S = Q K^T  (per wave: 16 q-rows x 64 kv-cols)
        f32x4 sv[4];
        #pragma unroll
        for (int ct = 0; ct < 4; ++ct) {
            f32x4 z = (f32x4){0.f, 0.f, 0.f, 0.f};
            z = __builtin_amdgcn_mfma_f32_16x16x32_bf16(qf0, *frg(Ks, ct * 16 + l15, g), z, 0, 0, 0);
            z = __builtin_amdgcn_mfma_f32_16x16x32_bf16(qf1, *frg(Ks, ct * 16 + l15, 4 + g), z, 0, 0, 0);
            sv[ct] = z;
        }

        // online softmax per C/D row (row = g*4 + i, cols across 16 lanes)
        #pragma unroll
        for (int i = 0; i < 4; ++i) {
            float mx = fmaxf(fmaxf(sv[0][i], sv[1][i]), fmaxf(sv[2][i], sv[3][i]));
            mx = fmaxf(mx, __shfl_xor(mx, 1));
            mx = fmaxf(mx, __shfl_xor(mx, 2));
            mx = fmaxf(mx, __shfl_xor(mx, 4));
            mx = fmaxf(mx, __shfl_xor(mx, 8));
            float mnew = fmaxf(m_r[i], mx);
            float corr = exp2f((m_r[i] - mnew) * CEXP);
            float pv[4], psum = 0.f;
            #pragma unroll
            for (int ct = 0; ct < 4; ++ct) {
                pv[ct] = exp2f((sv[ct][i] - mnew) * CEXP);
                psum += pv[ct];
            }
            psum += __shfl_xor(psum, 1);
            psum += __shfl_xor(psum, 2);
            psum += __shfl_xor(psum, 4);
            psum += __shfl_xor(psum, 8);
            l_r[i] = l_r[i] * corr + psum;
            m_r[i] = mnew;
            #pragma unroll
            for (int ct = 0; ct < 4; ++ct) oacc[ct][i] *= corr;
            int prow = (g << 2) + i;
            #pragma unroll
            for (int ct = 0; ct < 4; ++ct) {
                int col = ct * 16 + l15;
                Ps_w[(prow << 6) + (((col >> 3) ^ (prow & 7)) << 3) + (col & 7)] =
                    (short)f2bf(pv[ct]);
            }
        }

        // O += P V   (wave-local P; lgkmcnt ordering handled by compiler)
        short8 pf0 = *frg(Ps_w, l15, g);
        short8 pf1 = *frg(Ps_w, l15, 4 + g);
        #pragma unroll
        for (int ct = 0; ct < 4; ++ct) {
            oacc[ct] = __builtin_amdgcn_mfma_f32_16x16x32_bf16(pf0, *frg(Vs, ct * 16 + l15, g), oacc[ct], 0, 0, 0);
            oacc[ct] = __builtin_amdgcn_mfma_f32_16x16x32_bf16(pf1, *frg(Vs, ct * 16 + l15, 4 + g), oacc[ct], 0, 0, 0);
        }
    }

    float* Op = Ob + ((size_t)bb * N_ + qBase) * IN_ + h * DH_;
    #pragma unroll
    for (int i = 0; i < 4; ++i) {
        float inv = 1.0f / l_r[i];
        int row = w * 16 + (g << 2) + i;
        #pragma unroll
        for (int ct = 0; ct < 4; ++ct)
            Op[(size_t)row * IN_ + ct * 16 + l15] = oacc[ct][i] * inv;
    }
}

// ---------------------------------------------------------------------------
// y[b,o,n] = sum_c T3[b,n,c]*Wp[c,o] + bp[o] + x[b,o,n]  (transposed store)
__global__ __launch_bounds__(256)
void k_final_conv(const float* __restrict__ A, const float* __restrict__ Wp,
                  const float* __restrict__ bp, const float* __restrict__ x,
                  float* __restrict__ out) {
    __shared__ float As[16][68];
    __shared__ float Bs[16][68];
    __shared__ float Cs[64][68];
    int tid = threadIdx.x;
    int tx = tid & 15, ty = tid >> 4;
    int rowBase = blockIdx.y * 64;
    int colBase = blockIdx.x * 64;
    int arow = tid >> 2;
    int ak   = (tid & 3) << 2;
    int bk   = tid >> 4;
    int bcol = (tid & 15) << 2;
    float acc[4][4] = {};
    for (int k0 = 0; k0 < C_; k0 += 16) {
        float4 av = *(const float4*)(A + (size_t)(rowBase + arow) * C_ + k0 + ak);
        float4 bv = *(const float4*)(Wp + (size_t)(k0 + bk) * C_ + colBase + bcol);
        __syncthreads();
        As[ak + 0][arow] = av.x;
        As[ak + 1][arow] = av.y;
        As[ak + 2][arow] = av.z;
        As[ak + 3][arow] = av.w;
        *(float4*)&Bs[bk][bcol] = bv;
        __syncthreads();
        #pragma unroll
        for (int kk = 0; kk < 16; ++kk) {
            float4 a = *(const float4*)&As[kk][ty << 2];
            float4 b = *(const float4*)&Bs[kk][tx << 2];
            float ar[4] = {a.x, a.y, a.z, a.w};
            float br[4] = {b.x, b.y, b.z, b.w};
            #pragma unroll
            for (int i = 0; i < 4; ++i)
                #pragma unroll
                for (int j = 0; j < 4; ++j) acc[i][j] += ar[i] * br[j];
        }
    }
    __syncthreads();
    #pragma unroll
    for (int i = 0; i < 4; ++i)
        #pragma unroll
        for (int j = 0; j < 4; ++j)
            Cs[(tx << 2) + j][(ty << 2) + i] = acc[i][j];
    __syncthreads();
    int bb = rowBase / N_;
    int nBase = rowBase % N_;
    #pragma unroll
    for (int p = 0; p < 4; ++p) {
        int ol = (tid >> 4) + p * 16;
        int nl = (tid & 15) << 2;
        int o = colBase + ol;
        size_t oidx = ((size_t)(bb * C_ + o)) * N_ + nBase + nl;
        float4 cv = *(const float4*)&Cs[ol][nl];
        float4 xv = *(const float4*)(x + oidx);
        float bo_ = bp[o];
        *(float4*)(out + oidx) = make_float4(cv.x + bo_ + xv.x, cv.y + bo_ + xv.y,
                                             cv.z + bo_ + xv.z, cv.w + bo_ + xv.w);
    }
}

// ---------------------------------------------------------------------------
extern "C" void kernel_launch(void* const* d_in, const int* in_sizes, int n_in,
                              void* d_out, int out_size, void* d_ws, size_t ws_size,
                              hipStream_t stream) {
    (void)in_sizes; (void)n_in; (void)out_size; (void)ws_size;
    const float* x   = (const float*)d_in[0];
    const float* Wq  = (const float*)d_in[1];
    const float* Wk  = (const float*)d_in[2];
    const float* Wv  = (const float*)d_in[3];
    const float* Wo  = (const float*)d_in[4];
    const float* bo  = (const float*)d_in[5];
    const float* g1  = (const float*)d_in[6];
    const float* b1  = (const float*)d_in[7];
    const float* g2  = (const float*)d_in[8];
    const float* b2  = (const float*)d_in[9];
    const float* Wf1 = (const float*)d_in[10];
    const float* bf1 = (const float*)d_in[11];
    const float* Wf2 = (const float*)d_in[12];
    const float* bf2 = (const float*)d_in[13];
    const float* Wp  = (const float*)d_in[14];
    const float* bp  = (const float*)d_in[15];
    float* out = (float*)d_out;
    float* ws  = (float*)d_ws;

    float* T   = ws;                      // [9216,256] f32
    float* T2  = ws + 2359296;            // [9216,256] f32
    float* TN  = ws + 4718592;            // [9216,256] f32
    short* Qb  = (short*)(ws + 7077888);  // [9216,512] bf16
    short* Kb  = (short*)(ws + 9437184);  // [9216,512] bf16
    short* Vt  = (short*)(ws + 11796480); // [4,512,2304] bf16
    float* Ob  = ws + 14155776;           // [9216,512] f32
    float* F   = ws + 18874368;           // [9216,512] f32

    k_transpose_in<<<dim3(72, 8, 4), dim3(32, 8), 0, stream>>>(x, T);
    k_layernorm<<<2304, 256, 0, stream>>>(T, TN, g1, b1);
    k_gemm_qk<<<dim3(8, 144), 256, 0, stream>>>(TN, Wq, (unsigned short*)Qb, ROWS_, IN_, C_);
    k_gemm_qk<<<dim3(8, 144), 256, 0, stream>>>(TN, Wk, (unsigned short*)Kb, ROWS_, IN_, C_);
    k_gemm_vt<<<dim3(8, 144), 256, 0, stream>>>(TN, Wv, (unsigned short*)Vt, ROWS_, IN_, C_);
    k_flash_mfma<<<dim3(36, 32), 256, 0, stream>>>(Qb, Kb, Vt, Ob);
    k_gemm<2><<<dim3(4, 144), 256, 0, stream>>>(Ob, Wo, T2, bo, T, ROWS_, C_, IN_);
    k_layernorm<<<2304, 256, 0, stream>>>(T2, TN, g2, b2);
    k_gemm<3><<<dim3(8, 144), 256, 0, stream>>>(TN, Wf1, F, bf1, nullptr, ROWS_, IN_, C_);
    k_gemm<2><<<dim3(4, 144), 256, 0, stream>>>(F, Wf2, T, bf2, T2, ROWS_, C_, IN_);
    k_final_conv<<<dim3(4, 144), 256, 0, stream>>>(T, Wp, bp, x, out);
}

// Round 3
// 272.188 us; speedup vs baseline: 4.0966x; 1.8127x over previous
//
#include <hip/hip_runtime.h>
#include <math.h>

#define B_    4
#define C_    256
#define N_    2304      // 48*48 tokens
#define H_    8
#define DH_   64
#define IN_   512       // heads*dim_head
#define ROWS_ 9216      // B_*N_

typedef __attribute__((ext_vector_type(8))) short short8;
typedef __attribute__((ext_vector_type(4))) float f32x4;

__device__ __forceinline__ unsigned short f2bf(float f) {
    unsigned int u = __float_as_uint(f);
    u += 0x7fffu + ((u >> 16) & 1u);    // round-to-nearest-even
    return (unsigned short)(u >> 16);
}

__device__ __forceinline__ float gelu_exact(float x) {
    return 0.5f * x * (1.0f + erff(x * 0.70710678118654752440f));
}

// swizzled fragment pointer: rows of 64 shorts (128B = 8 chunks of 16B),
// chunk c of row r stored at c^(r&7).
__device__ __forceinline__ const short8* frg(const short* base, int row, int chunk) {
    return (const short8*)(base + (row << 6) + (((chunk) ^ (row & 7)) << 3));
}

// ---------------------------------------------------------------------------
// x[b][c][n] -> T[b][n][c]   (32x32 LDS tile transpose)
__global__ __launch_bounds__(256)
void k_transpose_in(const float* __restrict__ x, float* __restrict__ T) {
    __shared__ float tile[32][33];
    int bb = blockIdx.z;
    int nBase = blockIdx.x * 32;
    int cBase = blockIdx.y * 32;
    int tx = threadIdx.x, ty = threadIdx.y;
    const float* xp = x + (size_t)bb * C_ * N_;
    #pragma unroll
    for (int i = 0; i < 32; i += 8)
        tile[ty + i][tx] = xp[(size_t)(cBase + ty + i) * N_ + nBase + tx];
    __syncthreads();
    float* Tp = T + (size_t)bb * N_ * C_;
    #pragma unroll
    for (int i = 0; i < 32; i += 8)
        Tp[(size_t)(nBase + ty + i) * C_ + cBase + tx] = tile[tx][ty + i];
}

// ---------------------------------------------------------------------------
// Weight prep: W[K][N] fp32 -> Wt[N][K] bf16, all 7 weights in one launch.
__global__ __launch_bounds__(256)
void k_prep(const float* __restrict__ Wq, const float* __restrict__ Wk,
            const float* __restrict__ Wv, const float* __restrict__ Wo,
            const float* __restrict__ Wf1, const float* __restrict__ Wf2,
            const float* __restrict__ Wp,
            unsigned short* Wqh, unsigned short* Wkh, unsigned short* Wvh,
            unsigned short* Woh, unsigned short* Wf1h, unsigned short* Wf2h,
            unsigned short* Wph) {
    const float* src; unsigned short* dst; int K, N;
    switch (blockIdx.z) {
        case 0: src = Wq;  dst = Wqh;  K = 256; N = 512; break;
        case 1: src = Wk;  dst = Wkh;  K = 256; N = 512; break;
        case 2: src = Wv;  dst = Wvh;  K = 256; N = 512; break;
        case 3: src = Wo;  dst = Woh;  K = 512; N = 256; break;
        case 4: src = Wf1; dst = Wf1h; K = 256; N = 512; break;
        case 5: src = Wf2; dst = Wf2h; K = 512; N = 256; break;
        default: src = Wp; dst = Wph;  K = 256; N = 256; break;
    }
    int nBase = blockIdx.x * 32;   // dst row (= src col)
    int kBase = blockIdx.y * 32;   // dst col (= src row)
    if (nBase >= N || kBase >= K) return;
    __shared__ float tile[32][33];
    int tx = threadIdx.x, ty = threadIdx.y;
    #pragma unroll
    for (int i = 0; i < 32; i += 8)
        tile[ty + i][tx] = src[(size_t)(kBase + ty + i) * N + nBase + tx];
    __syncthreads();
    #pragma unroll
    for (int i = 0; i < 32; i += 8)
        dst[(size_t)(nBase + ty + i) * K + kBase + tx] = f2bf(tile[tx][ty + i]);
}

// ---------------------------------------------------------------------------
// row LayerNorm over C_=256, bf16 output: one wave per row, 4 floats/lane
__global__ __launch_bounds__(256)
void k_layernorm_bf16(const float* __restrict__ in, unsigned short* __restrict__ out,
                      const float* __restrict__ g, const float* __restrict__ b) {
    int wv = threadIdx.x >> 6;
    int lane = threadIdx.x & 63;
    int row = blockIdx.x * 4 + wv;
    float4 v = ((const float4*)(in + (size_t)row * C_))[lane];
    float s = v.x + v.y + v.z + v.w;
    #pragma unroll
    for (int m = 1; m < 64; m <<= 1) s += __shfl_xor(s, m);
    float mean = s * (1.0f / C_);
    float dx = v.x - mean, dy = v.y - mean, dz = v.z - mean, dw = v.w - mean;
    float s2 = dx * dx + dy * dy + dz * dz + dw * dw;
    #pragma unroll
    for (int m = 1; m < 64; m <<= 1) s2 += __shfl_xor(s2, m);
    float rs = rsqrtf(s2 * (1.0f / C_) + 1e-5f);
    float4 gv = ((const float4*)g)[lane];
    float4 bv = ((const float4*)b)[lane];
    ushort4 o;
    o.x = f2bf(dx * rs * gv.x + bv.x);
    o.y = f2bf(dy * rs * gv.y + bv.y);
    o.z = f2bf(dz * rs * gv.z + bv.z);
    o.w = f2bf(dw * rs * gv.w + bv.w);
    *(ushort4*)(out + (size_t)row * C_ + lane * 4) = o;
}

// ---------------------------------------------------------------------------
// MFMA GEMM: C[ar][br] = sum_k A[ar*K+k]*Bt[br*K+k].  128x128 tile, BK=64,
// 256 thr = 4 waves (2x2), 64x64 per wave. bf16 in, fp32 accum.
// EP: 0 bf16 out (ld=N) | 1 Vt bf16 out [(bb*512+ar)*2304+n] |
//     2 fp32 out +bias[br]+Res | 3 bf16 gelu(+bias[br]) |
//     4 bf16 +bias[br]+Res | 5 fp32 out[(bb*256+ar)*2304+n]+bias[ar]+Res[same]
template <int EP>
__global__ __launch_bounds__(256)
void k_gemm_mfma(const short* __restrict__ A, const short* __restrict__ Bt,
                 void* __restrict__ Out, const float* __restrict__ bias,
                 const float* __restrict__ Res, int M, int N, int K) {
    __shared__ __align__(16) short As[128 * 64];
    __shared__ __align__(16) short Bs[128 * 64];
    int tid = threadIdx.x;
    int w = tid >> 6;
    int lane = tid & 63;
    int l15 = lane & 15;
    int lg = lane >> 4;            // 0..3
    int wr = w >> 1, wc = w & 1;   // wave grid 2x2
    int rowBase = blockIdx.y * 128;
    int colBase = blockIdx.x * 128;

    f32x4 acc[4][4];
    #pragma unroll
    for (int m = 0; m < 4; ++m)
        #pragma unroll
        for (int n = 0; n < 4; ++n) acc[m][n] = (f32x4){0.f, 0.f, 0.f, 0.f};

    for (int k0 = 0; k0 < K; k0 += 64) {
        __syncthreads();
        #pragma unroll
        for (int it = 0; it < 4; ++it) {
            int id = it * 256 + tid;
            int r = id >> 3, c = id & 7;
            *(uint4*)(As + (r << 6) + (((c ^ (r & 7))) << 3)) =
                *(const uint4*)(A + (size_t)(rowBase + r) * K + k0 + c * 8);
            *(uint4*)(Bs + (r << 6) + (((c ^ (r & 7))) << 3)) =
                *(const uint4*)(Bt + (size_t)(colBase + r) * K + k0 + c * 8);
        }
        __syncthreads();
        short8 af[4][2], bf[4][2];
        #pragma unroll
        for (int m = 0; m < 4; ++m) {
            af[m][0] = *frg(As, wr * 64 + m * 16 + l15, lg);
            af[m][1] = *frg(As, wr * 64 + m * 16 + l15, 4 + lg);
        }
        #pragma unroll
        for (int n = 0; n < 4; ++n) {
            bf[n][0] = *frg(Bs, wc * 64 + n * 16 + l15, lg);
            bf[n][1] = *frg(Bs, wc * 64 + n * 16 + l15, 4 + lg);
        }
        #pragma unroll
        for (int m = 0; m < 4; ++m)
            #pragma unroll
            for (int n = 0; n < 4; ++n) {
                acc[m][n] = __builtin_amdgcn_mfma_f32_16x16x32_bf16(af[m][0], bf[n][0], acc[m][n], 0, 0, 0);
                acc[m][n] = __builtin_amdgcn_mfma_f32_16x16x32_bf16(af[m][1], bf[n][1], acc[m][n], 0, 0, 0);
            }
    }

    int arB = rowBase + wr * 64;
    int brB = colBase + wc * 64;
    int bb = 0;
    if (EP == 1 || EP == 5) bb = brB / N_;
    #pragma unroll
    for (int m = 0; m < 4; ++m) {
        #pragma unroll
        for (int i = 0; i < 4; ++i) {
            int ar = arB + m * 16 + lg * 4 + i;
            #pragma unroll
            for (int n = 0; n < 4; ++n) {
                int br = brB + n * 16 + l15;
                float v = acc[m][n][i];
                if constexpr (EP == 0) {
                    ((unsigned short*)Out)[(size_t)ar * N + br] = f2bf(v);
                } else if constexpr (EP == 1) {
                    ((unsigned short*)Out)[((size_t)(bb * IN_) + ar) * N_ + (br - bb * N_)] = f2bf(v);
                } else if constexpr (EP == 2) {
                    size_t o = (size_t)ar * N + br;
                    ((float*)Out)[o] = v + bias[br] + Res[o];
                } else if constexpr (EP == 3) {
                    ((unsigned short*)Out)[(size_t)ar * N + br] = f2bf(gelu_exact(v + bias[br]));
                } else if constexpr (EP == 4) {
                    size_t o = (size_t)ar * N + br;
                    ((unsigned short*)Out)[o] = f2bf(v + bias[br] + Res[o]);
                } else {
                    size_t o = ((size_t)(bb * C_) + ar) * N_ + (br - bb * N_);
                    ((float*)Out)[o] = v + bias[ar] + Res[o];
                }
            }
        }
    }
}

// ---------------------------------------------------------------------------
// MFMA flash attention (unchanged from round 2 except bf16 output).
#define CEXP 0.18033688f   // (1/sqrt(64)) * log2(e)

__global__ __launch_bounds__(256)
void k_flash_mfma(const short* __restrict__ Qb, const short* __restrict__ Kb,
                  const short* __restrict__ Vt, unsigned short* __restrict__ Ob) {
    __shared__ __align__(16) short Qs[64 * 64];
    __shared__ __align__(16) short Ks[64 * 64];
    __shared__ __align__(16) short Vs[64 * 64];   // [d][kv]
    __shared__ __align__(16) short Ps[4][16 * 64];
    int tid = threadIdx.x;
    int w = tid >> 6;
    int lane = tid & 63;
    int l15 = lane & 15;
    int g = lane >> 4;
    int bh = blockIdx.y;
    int bb = bh >> 3, h = bh & 7;
    int qBase = blockIdx.x * 64;

    const short* Qp = Qb + ((size_t)bb * N_ + qBase) * IN_ + h * DH_;
    const short* Kp = Kb + (size_t)bb * N_ * IN_ + h * DH_;
    const short* Vp = Vt + ((size_t)bb * IN_ + h * DH_) * N_;

    #pragma unroll
    for (int tt = 0; tt < 2; ++tt) {
        int t = tid + tt * 256;
        int r = t >> 3, c = t & 7;
        *(uint4*)(Qs + (r << 6) + ((c ^ (r & 7)) << 3)) =
            *(const uint4*)(Qp + (size_t)r * IN_ + c * 8);
    }
    __syncthreads();
    short8 qf0 = *frg(Qs, w * 16 + l15, g);
    short8 qf1 = *frg(Qs, w * 16 + l15, 4 + g);

    float m_r[4], l_r[4];
    f32x4 oacc[4];
    #pragma unroll
    for (int i = 0; i < 4; ++i) {
        m_r[i] = -1e30f; l_r[i] = 0.f;
        oacc[i] = (f32x4){0.f, 0.f, 0.f, 0.f};
    }
    short* Ps_w = Ps[w];

    for (int kt = 0; kt < N_; kt += 64) {
        __syncthreads();
        #pragma unroll
        for (int tt = 0; tt < 2; ++tt) {
            int t = tid + tt * 256;
            int r = t >> 3, c = t & 7;
            *(uint4*)(Ks + (r << 6) + ((c ^ (r & 7)) << 3)) =
                *(const uint4*)(Kp + (size_t)(kt + r) * IN_ + c * 8);
            *(uint4*)(Vs + (r << 6) + ((c ^ (r & 7)) << 3)) =
                *(const uint4*)(Vp + (size_t)r * N_ + kt + c * 8);
        }
        __syncthreads();

        f32x4 sv[4];
        #pragma unroll
        for (int ct = 0; ct < 4; ++ct) {
            f32x4 z = (f32x4){0.f, 0.f, 0.f, 0.f};
            z = __builtin_amdgcn_mfma_f32_16x16x32_bf16(qf0, *frg(Ks, ct * 16 + l15, g), z, 0, 0, 0);
            z = __builtin_amdgcn_mfma_f32_16x16x32_bf16(qf1, *frg(Ks, ct * 16 + l15, 4 + g), z, 0, 0, 0);
            sv[ct] = z;
        }

        #pragma unroll
        for (int i = 0; i < 4; ++i) {
            float mx = fmaxf(fmaxf(sv[0][i], sv[1][i]), fmaxf(sv[2][i], sv[3][i]));
            mx = fmaxf(mx, __shfl_xor(mx, 1));
            mx = fmaxf(mx, __shfl_xor(mx, 2));
            mx = fmaxf(mx, __shfl_xor(mx, 4));
            mx = fmaxf(mx, __shfl_xor(mx, 8));
            float mnew = fmaxf(m_r[i], mx);
            float corr = exp2f((m_r[i] - mnew) * CEXP);
            float pv[4], psum = 0.f;
            #pragma unroll
            for (int ct = 0; ct < 4; ++ct) {
                pv[ct] = exp2f((sv[ct][i] - mnew) * CEXP);
                psum += pv[ct];
            }
            psum += __shfl_xor(psum, 1);
            psum += __shfl_xor(psum, 2);
            psum += __shfl_xor(psum, 4);
            psum += __shfl_xor(psum, 8);
            l_r[i] = l_r[i] * corr + psum;
            m_r[i] = mnew;
            #pragma unroll
            for (int ct = 0; ct < 4; ++ct) oacc[ct][i] *= corr;
            int prow = (g << 2) + i;
            #pragma unroll
            for (int ct = 0; ct < 4; ++ct) {
                int col = ct * 16 + l15;
                Ps_w[(prow << 6) + (((col >> 3) ^ (prow & 7)) << 3) + (col & 7)] =
                    (short)f2bf(pv[ct]);
            }
        }

        short8 pf0 = *frg(Ps_w, l15, g);
        short8 pf1 = *frg(Ps_w, l15, 4 + g);
        #pragma unroll
        for (int ct = 0; ct < 4; ++ct) {
            oacc[ct] = __builtin_amdgcn_mfma_f32_16x16x32_bf16(pf0, *frg(Vs, ct * 16 + l15, g), oacc[ct], 0, 0, 0);
            oacc[ct] = __builtin_amdgcn_mfma_f32_16x16x32_bf16(pf1, *frg(Vs, ct * 16 + l15, 4 + g), oacc[ct], 0, 0, 0);
        }
    }

    unsigned short* Op = Ob + ((size_t)bb * N_ + qBase) * IN_ + h * DH_;
    #pragma unroll
    for (int i = 0; i < 4; ++i) {
        float inv = 1.0f / l_r[i];
        int row = w * 16 + (g << 2) + i;
        #pragma unroll
        for (int ct = 0; ct < 4; ++ct)
            Op[(size_t)row * IN_ + ct * 16 + l15] = f2bf(oacc[ct][i] * inv);
    }
}

// ---------------------------------------------------------------------------
extern "C" void kernel_launch(void* const* d_in, const int* in_sizes, int n_in,
                              void* d_out, int out_size, void* d_ws, size_t ws_size,
                              hipStream_t stream) {
    (void)in_sizes; (void)n_in; (void)out_size; (void)ws_size;
    const float* x   = (const float*)d_in[0];
    const float* Wq  = (const float*)d_in[1];
    const float* Wk  = (const float*)d_in[2];
    const float* Wv  = (const float*)d_in[3];
    const float* Wo  = (const float*)d_in[4];
    const float* bo  = (const float*)d_in[5];
    const float* g1  = (const float*)d_in[6];
    const float* b1  = (const float*)d_in[7];
    const float* g2  = (const float*)d_in[8];
    const float* b2  = (const float*)d_in[9];
    const float* Wf1 = (const float*)d_in[10];
    const float* bf1 = (const float*)d_in[11];
    const float* Wf2 = (const float*)d_in[12];
    const float* bf2 = (const float*)d_in[13];
    const float* Wp  = (const float*)d_in[14];
    const float* bp  = (const float*)d_in[15];
    float* out = (float*)d_out;
    float* ws  = (float*)d_ws;

    float* T    = ws;                                  // [9216,256] f32
    float* T2   = ws + 2359296;                        // [9216,256] f32
    unsigned short* TNh = (unsigned short*)(ws + 4718592);   // [9216,256] bf16
    short* Qb   = (short*)(ws + 5898240);              // [9216,512] bf16
    short* Kb   = (short*)(ws + 8257536);              // [9216,512] bf16
    short* Vt   = (short*)(ws + 10616832);             // [4,512,2304] bf16
    unsigned short* Obh = (unsigned short*)(ws + 12976128); // [9216,512] bf16
    short* F    = (short*)(ws + 15335424);             // [9216,512] bf16
    short* T3h  = (short*)(ws + 17694720);             // [9216,256] bf16
    unsigned short* Wqh  = (unsigned short*)(ws + 18874368);
    unsigned short* Wkh  = (unsigned short*)(ws + 18939904);
    unsigned short* Wvh  = (unsigned short*)(ws + 19005440);
    unsigned short* Woh  = (unsigned short*)(ws + 19070976);
    unsigned short* Wf1h = (unsigned short*)(ws + 19136512);
    unsigned short* Wf2h = (unsigned short*)(ws + 19202048);
    unsigned short* Wph  = (unsigned short*)(ws + 19267584);

    k_prep<<<dim3(16, 16, 7), dim3(32, 8), 0, stream>>>(Wq, Wk, Wv, Wo, Wf1, Wf2, Wp,
                                                        Wqh, Wkh, Wvh, Woh, Wf1h, Wf2h, Wph);
    k_transpose_in<<<dim3(72, 8, 4), dim3(32, 8), 0, stream>>>(x, T);
    k_layernorm_bf16<<<2304, 256, 0, stream>>>(T, TNh, g1, b1);
    k_gemm_mfma<0><<<dim3(4, 72), 256, 0, stream>>>((const short*)TNh, (const short*)Wqh, Qb, nullptr, nullptr, ROWS_, IN_, C_);
    k_gemm_mfma<0><<<dim3(4, 72), 256, 0, stream>>>((const short*)TNh, (const short*)Wkh, Kb, nullptr, nullptr, ROWS_, IN_, C_);
    k_gemm_mfma<1><<<dim3(72, 4), 256, 0, stream>>>((const short*)Wvh, (const short*)TNh, Vt, nullptr, nullptr, IN_, ROWS_, C_);
    k_flash_mfma<<<dim3(36, 32), 256, 0, stream>>>(Qb, Kb, Vt, Obh);
    k_gemm_mfma<2><<<dim3(2, 72), 256, 0, stream>>>((const short*)Obh, (const short*)Woh, T2, bo, T, ROWS_, C_, IN_);
    k_layernorm_bf16<<<2304, 256, 0, stream>>>(T2, TNh, g2, b2);
    k_gemm_mfma<3><<<dim3(4, 72), 256, 0, stream>>>((const short*)TNh, (const short*)Wf1h, F, bf1, nullptr, ROWS_, IN_, C_);
    k_gemm_mfma<4><<<dim3(2, 72), 256, 0, stream>>>((const short*)F, (const short*)Wf2h, T3h, bf2, T2, ROWS_, C_, IN_);
    k_gemm_mfma<5><<<dim3(72, 2), 256, 0, stream>>>((const short*)Wph, (const short*)T3h, out, bp, x, C_, ROWS_, C_);
}

// Round 4
// 250.677 us; speedup vs baseline: 4.4482x; 1.0858x over previous
//
#include <hip/hip_runtime.h>
#include <math.h>

#define B_    4
#define C_    256
#define N_    2304      // 48*48 tokens
#define H_    8
#define DH_   64
#define IN_   512       // heads*dim_head
#define ROWS_ 9216      // B_*N_

typedef __attribute__((ext_vector_type(8))) short short8;
typedef __attribute__((ext_vector_type(4))) float f32x4;

__device__ __forceinline__ unsigned short f2bf(float f) {
    unsigned int u = __float_as_uint(f);
    u += 0x7fffu + ((u >> 16) & 1u);    // round-to-nearest-even
    return (unsigned short)(u >> 16);
}

__device__ __forceinline__ float gelu_exact(float x) {
    return 0.5f * x * (1.0f + erff(x * 0.70710678118654752440f));
}

// swizzled fragment pointer: rows of 64 shorts (128B = 8 chunks of 16B),
// chunk c of row r stored at c^(r&7).
__device__ __forceinline__ const short8* frg(const short* base, int row, int chunk) {
    return (const short8*)(base + (row << 6) + (((chunk) ^ (row & 7)) << 3));
}

// ---------------------------------------------------------------------------
// x[b][c][n] -> T[b][n][c]   (32x32 LDS tile transpose)
__global__ __launch_bounds__(256)
void k_transpose_in(const float* __restrict__ x, float* __restrict__ T) {
    __shared__ float tile[32][33];
    int bb = blockIdx.z;
    int nBase = blockIdx.x * 32;
    int cBase = blockIdx.y * 32;
    int tx = threadIdx.x, ty = threadIdx.y;
    const float* xp = x + (size_t)bb * C_ * N_;
    #pragma unroll
    for (int i = 0; i < 32; i += 8)
        tile[ty + i][tx] = xp[(size_t)(cBase + ty + i) * N_ + nBase + tx];
    __syncthreads();
    float* Tp = T + (size_t)bb * N_ * C_;
    #pragma unroll
    for (int i = 0; i < 32; i += 8)
        Tp[(size_t)(nBase + ty + i) * C_ + cBase + tx] = tile[tx][ty + i];
}

// ---------------------------------------------------------------------------
// Weight prep: W[K][N] fp32 -> Wt[N][K] bf16, all 7 weights in one launch.
__global__ __launch_bounds__(256)
void k_prep(const float* __restrict__ Wq, const float* __restrict__ Wk,
            const float* __restrict__ Wv, const float* __restrict__ Wo,
            const float* __restrict__ Wf1, const float* __restrict__ Wf2,
            const float* __restrict__ Wp,
            unsigned short* Wqh, unsigned short* Wkh, unsigned short* Wvh,
            unsigned short* Woh, unsigned short* Wf1h, unsigned short* Wf2h,
            unsigned short* Wph) {
    const float* src; unsigned short* dst; int K, N;
    switch (blockIdx.z) {
        case 0: src = Wq;  dst = Wqh;  K = 256; N = 512; break;
        case 1: src = Wk;  dst = Wkh;  K = 256; N = 512; break;
        case 2: src = Wv;  dst = Wvh;  K = 256; N = 512; break;
        case 3: src = Wo;  dst = Woh;  K = 512; N = 256; break;
        case 4: src = Wf1; dst = Wf1h; K = 256; N = 512; break;
        case 5: src = Wf2; dst = Wf2h; K = 512; N = 256; break;
        default: src = Wp; dst = Wph;  K = 256; N = 256; break;
    }
    int nBase = blockIdx.x * 32;   // dst row (= src col)
    int kBase = blockIdx.y * 32;   // dst col (= src row)
    if (nBase >= N || kBase >= K) return;
    __shared__ float tile[32][33];
    int tx = threadIdx.x, ty = threadIdx.y;
    #pragma unroll
    for (int i = 0; i < 32; i += 8)
        tile[ty + i][tx] = src[(size_t)(kBase + ty + i) * N + nBase + tx];
    __syncthreads();
    #pragma unroll
    for (int i = 0; i < 32; i += 8)
        dst[(size_t)(nBase + ty + i) * K + kBase + tx] = f2bf(tile[tx][ty + i]);
}

// ---------------------------------------------------------------------------
// row LayerNorm over C_=256, bf16 output: one wave per row, 4 floats/lane
__global__ __launch_bounds__(256)
void k_layernorm_bf16(const float* __restrict__ in, unsigned short* __restrict__ out,
                      const float* __restrict__ g, const float* __restrict__ b) {
    int wv = threadIdx.x >> 6;
    int lane = threadIdx.x & 63;
    int row = blockIdx.x * 4 + wv;
    float4 v = ((const float4*)(in + (size_t)row * C_))[lane];
    float s = v.x + v.y + v.z + v.w;
    #pragma unroll
    for (int m = 1; m < 64; m <<= 1) s += __shfl_xor(s, m);
    float mean = s * (1.0f / C_);
    float dx = v.x - mean, dy = v.y - mean, dz = v.z - mean, dw = v.w - mean;
    float s2 = dx * dx + dy * dy + dz * dz + dw * dw;
    #pragma unroll
    for (int m = 1; m < 64; m <<= 1) s2 += __shfl_xor(s2, m);
    float rs = rsqrtf(s2 * (1.0f / C_) + 1e-5f);
    float4 gv = ((const float4*)g)[lane];
    float4 bv = ((const float4*)b)[lane];
    ushort4 o;
    o.x = f2bf(dx * rs * gv.x + bv.x);
    o.y = f2bf(dy * rs * gv.y + bv.y);
    o.z = f2bf(dz * rs * gv.z + bv.z);
    o.w = f2bf(dw * rs * gv.w + bv.w);
    *(ushort4*)(out + (size_t)row * C_ + lane * 4) = o;
}

// ---------------------------------------------------------------------------
// MFMA GEMM: C[ar][br] = sum_k A[ar*K+k]*Bt[br*K+k].  128x128 tile, BK=64,
// 256 thr = 4 waves (2x2), 64x64 per wave. bf16 in, fp32 accum.
// EP: 0 bf16 out (ld=N) | 1 Vt bf16 out [(bb*512+ar)*2304+n] |
//     2 fp32 out +bias[br]+Res | 3 bf16 gelu(+bias[br]) |
//     4 bf16 +bias[br]+Res | 5 fp32 out[(bb*256+ar)*2304+n]+bias[ar]+Res[same]
template <int EP>
__global__ __launch_bounds__(256)
void k_gemm_mfma(const short* __restrict__ A, const short* __restrict__ Bt,
                 void* __restrict__ Out, const float* __restrict__ bias,
                 const float* __restrict__ Res, int M, int N, int K) {
    __shared__ __align__(16) short As[128 * 64];
    __shared__ __align__(16) short Bs[128 * 64];
    int tid = threadIdx.x;
    int w = tid >> 6;
    int lane = tid & 63;
    int l15 = lane & 15;
    int lg = lane >> 4;            // 0..3
    int wr = w >> 1, wc = w & 1;   // wave grid 2x2
    int rowBase = blockIdx.y * 128;
    int colBase = blockIdx.x * 128;

    f32x4 acc[4][4];
    #pragma unroll
    for (int m = 0; m < 4; ++m)
        #pragma unroll
        for (int n = 0; n < 4; ++n) acc[m][n] = (f32x4){0.f, 0.f, 0.f, 0.f};

    for (int k0 = 0; k0 < K; k0 += 64) {
        __syncthreads();
        #pragma unroll
        for (int it = 0; it < 4; ++it) {
            int id = it * 256 + tid;
            int r = id >> 3, c = id & 7;
            *(uint4*)(As + (r << 6) + (((c ^ (r & 7))) << 3)) =
                *(const uint4*)(A + (size_t)(rowBase + r) * K + k0 + c * 8);
            *(uint4*)(Bs + (r << 6) + (((c ^ (r & 7))) << 3)) =
                *(const uint4*)(Bt + (size_t)(colBase + r) * K + k0 + c * 8);
        }
        __syncthreads();
        short8 af[4][2], bf[4][2];
        #pragma unroll
        for (int m = 0; m < 4; ++m) {
            af[m][0] = *frg(As, wr * 64 + m * 16 + l15, lg);
            af[m][1] = *frg(As, wr * 64 + m * 16 + l15, 4 + lg);
        }
        #pragma unroll
        for (int n = 0; n < 4; ++n) {
            bf[n][0] = *frg(Bs, wc * 64 + n * 16 + l15, lg);
            bf[n][1] = *frg(Bs, wc * 64 + n * 16 + l15, 4 + lg);
        }
        #pragma unroll
        for (int m = 0; m < 4; ++m)
            #pragma unroll
            for (int n = 0; n < 4; ++n) {
                acc[m][n] = __builtin_amdgcn_mfma_f32_16x16x32_bf16(af[m][0], bf[n][0], acc[m][n], 0, 0, 0);
                acc[m][n] = __builtin_amdgcn_mfma_f32_16x16x32_bf16(af[m][1], bf[n][1], acc[m][n], 0, 0, 0);
            }
    }

    int arB = rowBase + wr * 64;
    int brB = colBase + wc * 64;
    int bb = 0;
    if (EP == 1 || EP == 5) bb = brB / N_;
    #pragma unroll
    for (int m = 0; m < 4; ++m) {
        #pragma unroll
        for (int i = 0; i < 4; ++i) {
            int ar = arB + m * 16 + lg * 4 + i;
            #pragma unroll
            for (int n = 0; n < 4; ++n) {
                int br = brB + n * 16 + l15;
                float v = acc[m][n][i];
                if constexpr (EP == 0) {
                    ((unsigned short*)Out)[(size_t)ar * N + br] = f2bf(v);
                } else if constexpr (EP == 1) {
                    ((unsigned short*)Out)[((size_t)(bb * IN_) + ar) * N_ + (br - bb * N_)] = f2bf(v);
                } else if constexpr (EP == 2) {
                    size_t o = (size_t)ar * N + br;
                    ((float*)Out)[o] = v + bias[br] + Res[o];
                } else if constexpr (EP == 3) {
                    ((unsigned short*)Out)[(size_t)ar * N + br] = f2bf(gelu_exact(v + bias[br]));
                } else if constexpr (EP == 4) {
                    size_t o = (size_t)ar * N + br;
                    ((unsigned short*)Out)[o] = f2bf(v + bias[br] + Res[o]);
                } else {
                    size_t o = ((size_t)(bb * C_) + ar) * N_ + (br - bb * N_);
                    ((float*)Out)[o] = v + bias[ar] + Res[o];
                }
            }
        }
    }
}

// ---------------------------------------------------------------------------
// MFMA flash attention, S^T structure.
// Block = 256 thr = 4 waves; 128 q-rows per block (32 per wave, 2 subtiles
// of 16); KV tile = 64.  Swapped QK^T: S^T = mfma(K_frag, Q_frag) puts a
// full q-row (16 of 64 kv) in-lane at q = lane&15 -> row reduce is in-lane
// + 2 shfl_xor.  P packed bf16x2 through wave-private LDS (aliases Q
// staging).  Defer-max (THR=8 raw-logit units) skips rescale in steady state.
#define CEXP 0.18033688f   // (1/sqrt(64)) * log2(e)

__global__ __launch_bounds__(256)
void k_flash_mfma(const short* __restrict__ Qb, const short* __restrict__ Kb,
                  const short* __restrict__ Vt, unsigned short* __restrict__ Ob) {
    __shared__ __align__(16) short QP[128 * 64];  // Q staging, then P (per wave)
    __shared__ __align__(16) short Ks[64 * 64];   // [kv][d] swizzled
    __shared__ __align__(16) short Vs[64 * 64];   // [d][kv] swizzled
    int tid = threadIdx.x;
    int w = tid >> 6;
    int lane = tid & 63;
    int l15 = lane & 15;
    int g = lane >> 4;          // 0..3
    int bh = blockIdx.y;
    int bb = bh >> 3, h = bh & 7;
    int qBase = blockIdx.x * 128;

    const short* Qp = Qb + ((size_t)bb * N_ + qBase) * IN_ + h * DH_;
    const short* Kp = Kb + (size_t)bb * N_ * IN_ + h * DH_;
    const short* Vp = Vt + ((size_t)bb * IN_ + h * DH_) * N_;

    // stage Q (swizzled): 128 rows x 8 chunks = 1024, 4 per thread
    #pragma unroll
    for (int tt = 0; tt < 4; ++tt) {
        int t = tid + tt * 256;
        int r = t >> 3, c = t & 7;
        *(uint4*)(QP + (r << 6) + ((c ^ (r & 7)) << 3)) =
            *(const uint4*)(Qp + (size_t)r * IN_ + c * 8);
    }
    __syncthreads();
    short8 qf[2][2];
    #pragma unroll
    for (int s = 0; s < 2; ++s) {
        qf[s][0] = *frg(QP, w * 32 + s * 16 + l15, g);
        qf[s][1] = *frg(QP, w * 32 + s * 16 + l15, 4 + g);
    }
    short* Ps_w = QP + w * 32 * 64;   // wave-private P region (aliases Q)

    float m_r[2], l_r[2];
    f32x4 oacc[2][4];
    #pragma unroll
    for (int s = 0; s < 2; ++s) {
        m_r[s] = -1e30f; l_r[s] = 0.f;
        #pragma unroll
        for (int d = 0; d < 4; ++d) oacc[s][d] = (f32x4){0.f, 0.f, 0.f, 0.f};
    }

    for (int kt = 0; kt < N_; kt += 64) {
        __syncthreads();   // prior tile reads (and initial Q frag reads) done
        #pragma unroll
        for (int tt = 0; tt < 2; ++tt) {
            int t = tid + tt * 256;
            int r = t >> 3, c = t & 7;
            *(uint4*)(Ks + (r << 6) + ((c ^ (r & 7)) << 3)) =
                *(const uint4*)(Kp + (size_t)(kt + r) * IN_ + c * 8);
            *(uint4*)(Vs + (r << 6) + ((c ^ (r & 7)) << 3)) =
                *(const uint4*)(Vp + (size_t)r * N_ + kt + c * 8);
        }
        __syncthreads();

        // S^T tiles: st[s][ct][i] = S[q = l15 (in qsub s)][kv = ct*16 + g*4 + i]
        f32x4 st[2][4];
        #pragma unroll
        for (int ct = 0; ct < 4; ++ct) {
            short8 kf0 = *frg(Ks, ct * 16 + l15, g);
            short8 kf1 = *frg(Ks, ct * 16 + l15, 4 + g);
            #pragma unroll
            for (int s = 0; s < 2; ++s) {
                f32x4 z = (f32x4){0.f, 0.f, 0.f, 0.f};
                z = __builtin_amdgcn_mfma_f32_16x16x32_bf16(kf0, qf[s][0], z, 0, 0, 0);
                z = __builtin_amdgcn_mfma_f32_16x16x32_bf16(kf1, qf[s][1], z, 0, 0, 0);
                st[s][ct] = z;
            }
        }

        #pragma unroll
        for (int s = 0; s < 2; ++s) {
            // row max: in-lane 16 + xor16 + xor32 (replicated across g-groups)
            float mx = st[s][0][0];
            #pragma unroll
            for (int ct = 0; ct < 4; ++ct)
                #pragma unroll
                for (int i = 0; i < 4; ++i) mx = fmaxf(mx, st[s][ct][i]);
            mx = fmaxf(mx, __shfl_xor(mx, 16));
            mx = fmaxf(mx, __shfl_xor(mx, 32));
            // defer-max: rescale only if some row grew past m+8 (raw units)
            if (__ballot(mx > m_r[s] + 8.0f) != 0ULL) {
                float mnew = fmaxf(m_r[s], mx);
                float corr = exp2f((m_r[s] - mnew) * CEXP);
                m_r[s] = mnew;
                l_r[s] *= corr;
                #pragma unroll
                for (int i = 0; i < 4; ++i) {
                    float ci = __shfl(corr, (g << 4) + (g << 2) + i);
                    #pragma unroll
                    for (int d = 0; d < 4; ++d) oacc[s][d][i] *= ci;
                }
            }
            // p = exp2((s - m)*CEXP), sum, pack to LDS
            float p[16];
            float psum = 0.f;
            #pragma unroll
            for (int ct = 0; ct < 4; ++ct)
                #pragma unroll
                for (int i = 0; i < 4; ++i) {
                    float pv = exp2f((st[s][ct][i] - m_r[s]) * CEXP);
                    p[ct * 4 + i] = pv;
                    psum += pv;
                }
            psum += __shfl_xor(psum, 16);
            psum += __shfl_xor(psum, 32);
            l_r[s] += psum;
            int qrow = s * 16 + l15;
            int rswz = qrow & 7;
            #pragma unroll
            for (int ct = 0; ct < 4; ++ct)
                #pragma unroll
                for (int pr = 0; pr < 2; ++pr) {
                    unsigned u0 = __float_as_uint(p[ct * 4 + 2 * pr]) + 0x8000u;
                    unsigned u1 = __float_as_uint(p[ct * 4 + 2 * pr + 1]) + 0x8000u;
                    unsigned pkd = __builtin_amdgcn_perm(u1, u0, 0x07060302u);
                    int ko = ct * 16 + (g << 2) + 2 * pr;
                    *(unsigned*)(Ps_w + (qrow << 6) + (((ko >> 3) ^ rswz) << 3) + (ko & 7)) = pkd;
                }
        }

        // O += P V : A = P rows (q), B = V^T rows (d), both kv-contiguous
        short8 pf[2][2];
        #pragma unroll
        for (int s = 0; s < 2; ++s) {
            pf[s][0] = *frg(Ps_w, s * 16 + l15, g);
            pf[s][1] = *frg(Ps_w, s * 16 + l15, 4 + g);
        }
        #pragma unroll
        for (int d = 0; d < 4; ++d) {
            short8 vf0 = *frg(Vs, d * 16 + l15, g);
            short8 vf1 = *frg(Vs, d * 16 + l15, 4 + g);
            #pragma unroll
            for (int s = 0; s < 2; ++s) {
                oacc[s][d] = __builtin_amdgcn_mfma_f32_16x16x32_bf16(pf[s][0], vf0, oacc[s][d], 0, 0, 0);
                oacc[s][d] = __builtin_amdgcn_mfma_f32_16x16x32_bf16(pf[s][1], vf1, oacc[s][d], 0, 0, 0);
            }
        }
    }

    unsigned short* Op = Ob + ((size_t)bb * N_ + qBase + w * 32) * IN_ + h * DH_;
    #pragma unroll
    for (int s = 0; s < 2; ++s) {
        #pragma unroll
        for (int i = 0; i < 4; ++i) {
            float lv = __shfl(l_r[s], (g << 4) + (g << 2) + i);
            float inv = 1.0f / lv;
            int row = s * 16 + (g << 2) + i;
            #pragma unroll
            for (int d = 0; d < 4; ++d)
                Op[(size_t)row * IN_ + d * 16 + l15] = f2bf(oacc[s][d][i] * inv);
        }
    }
}

// ---------------------------------------------------------------------------
extern "C" void kernel_launch(void* const* d_in, const int* in_sizes, int n_in,
                              void* d_out, int out_size, void* d_ws, size_t ws_size,
                              hipStream_t stream) {
    (void)in_sizes; (void)n_in; (void)out_size; (void)ws_size;
    const float* x   = (const float*)d_in[0];
    const float* Wq  = (const float*)d_in[1];
    const float* Wk  = (const float*)d_in[2];
    const float* Wv  = (const float*)d_in[3];
    const float* Wo  = (const float*)d_in[4];
    const float* bo  = (const float*)d_in[5];
    const float* g1  = (const float*)d_in[6];
    const float* b1  = (const float*)d_in[7];
    const float* g2  = (const float*)d_in[8];
    const float* b2  = (const float*)d_in[9];
    const float* Wf1 = (const float*)d_in[10];
    const float* bf1 = (const float*)d_in[11];
    const float* Wf2 = (const float*)d_in[12];
    const float* bf2 = (const float*)d_in[13];
    const float* Wp  = (const float*)d_in[14];
    const float* bp  = (const float*)d_in[15];
    float* out = (float*)d_out;
    float* ws  = (float*)d_ws;

    float* T    = ws;                                  // [9216,256] f32
    float* T2   = ws + 2359296;                        // [9216,256] f32
    unsigned short* TNh = (unsigned short*)(ws + 4718592);   // [9216,256] bf16
    short* Qb   = (short*)(ws + 5898240);              // [9216,512] bf16
    short* Kb   = (short*)(ws + 8257536);              // [9216,512] bf16
    short* Vt   = (short*)(ws + 10616832);             // [4,512,2304] bf16
    unsigned short* Obh = (unsigned short*)(ws + 12976128); // [9216,512] bf16
    short* F    = (short*)(ws + 15335424);             // [9216,512] bf16
    short* T3h  = (short*)(ws + 17694720);             // [9216,256] bf16
    unsigned short* Wqh  = (unsigned short*)(ws + 18874368);
    unsigned short* Wkh  = (unsigned short*)(ws + 18939904);
    unsigned short* Wvh  = (unsigned short*)(ws + 19005440);
    unsigned short* Woh  = (unsigned short*)(ws + 19070976);
    unsigned short* Wf1h = (unsigned short*)(ws + 19136512);
    unsigned short* Wf2h = (unsigned short*)(ws + 19202048);
    unsigned short* Wph  = (unsigned short*)(ws + 19267584);

    k_prep<<<dim3(16, 16, 7), dim3(32, 8), 0, stream>>>(Wq, Wk, Wv, Wo, Wf1, Wf2, Wp,
                                                        Wqh, Wkh, Wvh, Woh, Wf1h, Wf2h, Wph);
    k_transpose_in<<<dim3(72, 8, 4), dim3(32, 8), 0, stream>>>(x, T);
    k_layernorm_bf16<<<2304, 256, 0, stream>>>(T, TNh, g1, b1);
    k_gemm_mfma<0><<<dim3(4, 72), 256, 0, stream>>>((const short*)TNh, (const short*)Wqh, Qb, nullptr, nullptr, ROWS_, IN_, C_);
    k_gemm_mfma<0><<<dim3(4, 72), 256, 0, stream>>>((const short*)TNh, (const short*)Wkh, Kb, nullptr, nullptr, ROWS_, IN_, C_);
    k_gemm_mfma<1><<<dim3(72, 4), 256, 0, stream>>>((const short*)Wvh, (const short*)TNh, Vt, nullptr, nullptr, IN_, ROWS_, C_);
    k_flash_mfma<<<dim3(18, 32), 256, 0, stream>>>(Qb, Kb, Vt, Obh);
    k_gemm_mfma<2><<<dim3(2, 72), 256, 0, stream>>>((const short*)Obh, (const short*)Woh, T2, bo, T, ROWS_, C_, IN_);
    k_layernorm_bf16<<<2304, 256, 0, stream>>>(T2, TNh, g2, b2);
    k_gemm_mfma<3><<<dim3(4, 72), 256, 0, stream>>>((const short*)TNh, (const short*)Wf1h, F, bf1, nullptr, ROWS_, IN_, C_);
    k_gemm_mfma<4><<<dim3(2, 72), 256, 0, stream>>>((const short*)F, (const short*)Wf2h, T3h, bf2, T2, ROWS_, C_, IN_);
    k_gemm_mfma<5><<<dim3(72, 2), 256, 0, stream>>>((const short*)Wph, (const short*)T3h, out, bp, x, C_, ROWS_, C_);
}